// Round 4
// baseline (181.695 us; speedup 1.0000x reference)
//
#include <hip/hip_runtime.h>

// MultiHeadAttn1D: N=4, C=256, T=2048, H=8, dk=dv=32.
// ws layout (bytes):
//   [0   , 4Mi ) Q_ws  bf16 B-frag (16x16x32): [nh(32)][qtile(128)][lane(64)][8]
//                lane=(t&15)+16*(d>>3), j=d&7   (Q pre-scaled by log2e/sqrt(32))
//   [4Mi , 8Mi ) K_ws  bf16 A-frag (16x16x32): [nh][ktile(128)][lane][8]
//                lane=(s&15)+16*(d>>3), j=d&7
//   [8Mi ,12Mi ) V_ws  bf16 B-frag (16x16x16): [nh][kb(32)][dt(2)][sbp(2)][lane][8]
//                lane=(d&15)+16*((s>>2)&3), short=(s>>4&1)*4 + (s&3)
//   [12Mi,16Mi ) Xb    bf16 A-frag x: [n(4)][tt(128)][kc(8)][lane][8]
//   [16Mi,16.4Mi) Wb   bf16 B-frag W: [wi(3)][ot(16)][kc(8)][lane][8]
//   [20Mi,20Mi+KS*8Mi)   O_part fp32 [ks][nh][d(32)][t(2048)]      (KS>1 only)
//   [20Mi+KS*8Mi, +KS*256Ki) l_part fp32 [ks][nh][t(2048)]         (KS>1 only)

typedef float f32x4 __attribute__((ext_vector_type(4)));
typedef short short8 __attribute__((ext_vector_type(8)));
typedef short short4v __attribute__((ext_vector_type(4)));

#define WS_Q 0u
#define WS_K (4u << 20)
#define WS_V (8u << 20)
#define WS_X (12u << 20)
#define WS_W (16u << 20)
#define WS_OP (20u << 20)

__device__ __forceinline__ unsigned short f2bf(float f) {
  unsigned int u = __builtin_bit_cast(unsigned int, f);
  u += 0x7FFFu + ((u >> 16) & 1u);
  return (unsigned short)(u >> 16);
}

// pack two floats to bf16 (round-nearest) into one dword: [bf(a) | bf(b)<<16]
__device__ __forceinline__ int pack_bf16rn(float a, float b) {
  unsigned int ua = __builtin_bit_cast(unsigned int, a) + 0x8000u;
  unsigned int ub = __builtin_bit_cast(unsigned int, b) + 0x8000u;
  return __builtin_amdgcn_perm(ub, ua, 0x07060302);
}

// ---------------- pack: x -> Xb (bf16 A-frags), W -> Wb (bf16 B-frags) ---------
__global__ __launch_bounds__(256) void pack_kernel(
    const float* __restrict__ x, const float* __restrict__ Wq,
    const float* __restrict__ Wk, const float* __restrict__ Wv,
    unsigned short* __restrict__ ws) {
  const int tid = threadIdx.x;
  const int lane = tid & 63;
  const int wv = tid >> 6;
  const int lc = lane & 15, lq = lane >> 4;
  const int b = blockIdx.x;
  alignas(16) unsigned short tmp[8];
  if (b < 1024) {
    const int r = b * 4 + wv;  // 0..4095 = (n,tt,kc)
    const int kc = r & 7, tt = (r >> 3) & 127, n = r >> 10;
    const int t = tt * 16 + lc;
    const int c0 = kc * 32 + lq * 8;
    const float* src = x + (size_t)(n * 256 + c0) * 2048 + t;
#pragma unroll
    for (int j = 0; j < 8; ++j) tmp[j] = f2bf(src[(size_t)j * 2048]);
    unsigned short* dst = ws + (WS_X >> 1) + (size_t)r * 512 + lane * 8;
    *(int4*)dst = *(const int4*)tmp;
  } else {
    const int r = (b - 1024) * 4 + wv;  // 0..383 = (wi,ot,kc)
    const int kc = r & 7, ot = (r >> 3) & 15, wi = r >> 7;
    const float* W = (wi == 0) ? Wq : (wi == 1) ? Wk : Wv;
    // fold softmax scale * log2(e) into Wq so attention uses exp2 with no extra mul
    const float scale = (wi == 0) ? 0.25503492f : 1.0f;  // log2(e)/sqrt(32)
    const int o = ot * 16 + lc;
    const int c0 = kc * 32 + lq * 8;
    const float* src = W + o * 256 + c0;
#pragma unroll
    for (int j = 0; j < 8; ++j) tmp[j] = f2bf(src[j] * scale);
    unsigned short* dst = ws + (WS_W >> 1) + (size_t)r * 512 + lane * 8;
    *(int4*)dst = *(const int4*)tmp;
  }
}

// ---------------- projection GEMM: Q/K/V = W * x, frag-packed outputs ----------
__global__ __launch_bounds__(256) void proj_kernel(unsigned short* __restrict__ ws) {
  __shared__ unsigned short eps[4][2048];  // per-wave 4KB swizzle buffer (Q/K only)
  const int tid = threadIdx.x, lane = tid & 63, w = tid >> 6;
  const int lc = lane & 15, lq = lane >> 4;
  const int tt2 = blockIdx.x;  // 0..63 : t-range of 32
  const int n = blockIdx.y;    // 0..3
  const int wi = blockIdx.z;   // 0=Q 1=K 2=V
  const unsigned short* Xb = ws + (WS_X >> 1);
  const unsigned short* Wb = ws + (WS_W >> 1);

  short8 af[2][8];
#pragma unroll
  for (int mt = 0; mt < 2; ++mt)
#pragma unroll
    for (int kc = 0; kc < 8; ++kc)
      af[mt][kc] = *(const short8*)(Xb + ((size_t)((n * 128 + tt2 * 2 + mt) * 8 + kc) * 512 + lane * 8));

  f32x4 acc[2][4];
#pragma unroll
  for (int mt = 0; mt < 2; ++mt)
#pragma unroll
    for (int nt = 0; nt < 4; ++nt) {
      f32x4 z = {0.f, 0.f, 0.f, 0.f};
      acc[mt][nt] = z;
    }

#pragma unroll
  for (int kc = 0; kc < 8; ++kc) {
    short8 bf[4];
#pragma unroll
    for (int nt = 0; nt < 4; ++nt)
      bf[nt] = *(const short8*)(Wb + ((size_t)((wi * 16 + w * 4 + nt) * 8 + kc) * 512 + lane * 8));
#pragma unroll
    for (int mt = 0; mt < 2; ++mt)
#pragma unroll
      for (int nt = 0; nt < 4; ++nt)
        acc[mt][nt] = __builtin_amdgcn_mfma_f32_16x16x32_bf16(af[mt][kc], bf[nt], acc[mt][nt], 0, 0, 0);
  }

  // C layout: value (mt,nt,r) at lane(lc,lq) is element (t = tt2*32+mt*16+lq*4+r,
  //                                                      o = w*64+nt*16+lc)
  if (wi < 2) {
    // Q/K: target lane'=(t&15)+16*(d>>3), j=d&7  -> transpose via swizzled LDS
    unsigned short* ep = eps[w];
#pragma unroll
    for (int mt = 0; mt < 2; ++mt)
#pragma unroll
      for (int nt = 0; nt < 4; ++nt) {
        const int m2 = ((nt & 1) << 1) | (lc >> 3);
        const int base = ((mt * 2 + (nt >> 1)) << 9) + (m2 << 7) + (lq << 5) + (lc & 7);
#pragma unroll
        for (int r = 0; r < 4; ++r)
          ep[base + ((r ^ m2) << 3)] = f2bf(acc[mt][nt][r]);
      }
    const int swzl = lane ^ (lane >> 4);
    unsigned short* dst = ws + ((wi == 0) ? (WS_Q >> 1) : (WS_K >> 1));
#pragma unroll
    for (int rl = 0; rl < 4; ++rl) {
      int4 v = *(const int4*)(ep + (rl << 9) + swzl * 8);
      const int mt = rl >> 1, hh = rl & 1;
      const int nh = n * 8 + w * 2 + hh;
      const int ttg = tt2 * 2 + mt;
      *(int4*)(dst + ((size_t)(nh * 128 + ttg) * 64 + lane) * 8) = v;
    }
  } else {
    // V: target [nh][kb][dt][sbp][lane][half*4+j] -- lane mapping is IDENTITY.
    const int kb = tt2 >> 1, sbp = tt2 & 1;
#pragma unroll
    for (int nt = 0; nt < 4; ++nt) {
      const int nh = n * 8 + w * 2 + (nt >> 1);
      const int dt = nt & 1;
      alignas(16) unsigned short tmp[8];
#pragma unroll
      for (int mt = 0; mt < 2; ++mt)
#pragma unroll
        for (int r = 0; r < 4; ++r) tmp[mt * 4 + r] = f2bf(acc[mt][nt][r]);
      unsigned short* dstv = ws + (WS_V >> 1) +
          ((size_t)((((nh * 32 + kb) * 2 + dt) * 2 + sbp)) * 64 + lane) * 8;
      *(int4*)dstv = *(const int4*)tmp;
    }
  }
}

// ------- fused flash attention: split-K, 4 waves share LDS-staged K/V ---------
// Block = 256 threads = 4 waves, same (nh,ks), different q-ranges. K/V tile
// (8KB/iter) staged cooperatively in double-buffered LDS: 4x less L2 traffic
// than private loads. One __syncthreads per iter; 8 blocks/CU hide the barrier.
template <int KS>
__global__ __launch_bounds__(256, 6) void attn_kernel(
    const unsigned short* __restrict__ ws, float* __restrict__ out,
    float* __restrict__ opart, float* __restrict__ lpart) {
  __shared__ __align__(16) char smem[16384];  // 2 x (4K K | 4K V)
  const int tid = threadIdx.x;
  const int lane = tid & 63, wv = tid >> 6;
  const int lc = lane & 15, quad = lane >> 4;
  const int qw = blockIdx.x * 4 + wv;  // 0..63 -> q rows qw*32 .. +31
  const int nh = blockIdx.y;           // 0..31
  const int ks = blockIdx.z;           // 0..KS-1
  constexpr int NKB = 32 / KS;

  const unsigned short* Qw = ws + (WS_Q >> 1) + ((size_t)(nh * 128 + qw * 2)) * 512;
  const char* Kc = (const char*)ws + WS_K + (size_t)nh * 131072 + (size_t)(ks * NKB) * 4096;
  const char* Vc = (const char*)ws + WS_V + (size_t)nh * 131072 + (size_t)(ks * NKB) * 4096;

  // Q B-frags (16x16x32): n=query on lane&15, k=dk on quad*8+j. Loaded once.
  short8 qf[2];
  qf[0] = *(const short8*)(Qw + lane * 8);
  qf[1] = *(const short8*)(Qw + 512 + lane * 8);

  // stage first K/V block: one int4 per thread each (4KB K + 4KB V)
  *(int4*)(smem + tid * 16) = *(const int4*)(Kc + tid * 16);
  *(int4*)(smem + 4096 + tid * 16) = *(const int4*)(Vc + tid * 16);
  __syncthreads();

  f32x4 acc[2][2];
#pragma unroll
  for (int mt = 0; mt < 2; ++mt)
#pragma unroll
    for (int dt = 0; dt < 2; ++dt) {
      f32x4 z = {0.f, 0.f, 0.f, 0.f};
      acc[mt][dt] = z;
    }
  float lsum[2] = {0.f, 0.f};

  for (int it = 0; it < NKB; ++it) {
    int4 pk, pv;
    const bool pre = (it + 1 < NKB);
    if (pre) {  // register prefetch of next K/V block, overlaps compute
      pk = *(const int4*)(Kc + (it + 1) * 4096 + tid * 16);
      pv = *(const int4*)(Vc + (it + 1) * 4096 + tid * 16);
    }
    const unsigned short* kb = (const unsigned short*)(smem + (it & 1) * 8192);
    const unsigned short* vb = kb + 2048;

    short8 kf[4], vvr[4];
#pragma unroll
    for (int sb = 0; sb < 4; ++sb) kf[sb] = *(const short8*)(kb + sb * 512 + lane * 8);
#pragma unroll
    for (int u = 0; u < 4; ++u) vvr[u] = *(const short8*)(vb + u * 512 + lane * 8);

    // S^T = K * Q^T via 16x16x32: A=K-frag (m=key), B=Q-frag (n=query)
    // C-layout of S^T (col=query, row=key quad*4+r) == A-frag layout of 16x16x16.
    short4v pf[2][4];
#pragma unroll
    for (int mt = 0; mt < 2; ++mt) {
      f32x4 st[4];
#pragma unroll
      for (int sb = 0; sb < 4; ++sb) {
        f32x4 z = {0.f, 0.f, 0.f, 0.f};
        st[sb] = __builtin_amdgcn_mfma_f32_16x16x32_bf16(kf[sb], qf[mt], z, 0, 0, 0);
      }
#pragma unroll
      for (int sb = 0; sb < 4; ++sb) {
        float p0 = __builtin_amdgcn_exp2f(st[sb][0]);
        float p1 = __builtin_amdgcn_exp2f(st[sb][1]);
        float p2 = __builtin_amdgcn_exp2f(st[sb][2]);
        float p3 = __builtin_amdgcn_exp2f(st[sb][3]);
        lsum[mt] += (p0 + p1) + (p2 + p3);
        int2 pi;
        pi.x = pack_bf16rn(p0, p1);
        pi.y = pack_bf16rn(p2, p3);
        pf[mt][sb] = __builtin_bit_cast(short4v, pi);
      }
    }

    // O += P * V via 16x16x16 (V B-frag prepacked: n=d on lane&15, k=key)
    short4v vf[4][2];
#pragma unroll
    for (int dt = 0; dt < 2; ++dt)
#pragma unroll
      for (int sbp = 0; sbp < 2; ++sbp) {
        short8 t = vvr[dt * 2 + sbp];
        vf[sbp * 2 + 0][dt] = __builtin_shufflevector(t, t, 0, 1, 2, 3);
        vf[sbp * 2 + 1][dt] = __builtin_shufflevector(t, t, 4, 5, 6, 7);
      }
#pragma unroll
    for (int sb = 0; sb < 4; ++sb)
#pragma unroll
      for (int mt = 0; mt < 2; ++mt) {
        acc[mt][0] = __builtin_amdgcn_mfma_f32_16x16x16bf16_1k(pf[mt][sb], vf[sb][0], acc[mt][0], 0, 0, 0);
        acc[mt][1] = __builtin_amdgcn_mfma_f32_16x16x16bf16_1k(pf[mt][sb], vf[sb][1], acc[mt][1], 0, 0, 0);
      }

    if (pre) {
      char* db = smem + ((it + 1) & 1) * 8192;
      *(int4*)(db + tid * 16) = pk;
      *(int4*)(db + 4096 + tid * 16) = pv;
    }
    __syncthreads();
  }

  // finish row sums across quads (each lane then has full sum for query lc of its mt)
#pragma unroll
  for (int mt = 0; mt < 2; ++mt) {
    lsum[mt] += __shfl_xor(lsum[mt], 16);
    lsum[mt] += __shfl_xor(lsum[mt], 32);
  }

  if constexpr (KS == 1) {
    // normalize + direct store. acc C-layout: col=lc=d, row=quad*4+r=q (+mt*16)
    const int chbase = (nh >> 3) * 256 + (nh & 7) * 32;
#pragma unroll
    for (int mt = 0; mt < 2; ++mt) {
      float is[4];
#pragma unroll
      for (int r = 0; r < 4; ++r) is[r] = 1.0f / __shfl(lsum[mt], quad * 4 + r);
      const int tb = qw * 32 + mt * 16 + quad * 4;
#pragma unroll
      for (int dt = 0; dt < 2; ++dt) {
        f32x4 ov;
#pragma unroll
        for (int r = 0; r < 4; ++r) ov[r] = acc[mt][dt][r] * is[r];
        *(f32x4*)(out + (size_t)(chbase + dt * 16 + lc) * 2048 + tb) = ov;
      }
    }
  } else {
    // store UNnormalized partials; finalize kernel combines.
    const size_t ob = (size_t)(ks * 32 + nh) * 32 * 2048;
#pragma unroll
    for (int mt = 0; mt < 2; ++mt) {
      const int tb = qw * 32 + mt * 16 + quad * 4;
#pragma unroll
      for (int dt = 0; dt < 2; ++dt)
        *(f32x4*)(opart + ob + (size_t)(dt * 16 + lc) * 2048 + tb) = acc[mt][dt];
      if (quad == 0)
        lpart[(size_t)(ks * 32 + nh) * 2048 + qw * 32 + mt * 16 + lc] = lsum[mt];
    }
  }
}

// ---------------- finalize: out = (sum_ks O_part) / (sum_ks l_part) -----------
template <int KS>
__global__ __launch_bounds__(256) void finalize_kernel(
    const float* __restrict__ opart, const float* __restrict__ lpart,
    float* __restrict__ out) {
  const int f = blockIdx.x * 256 + threadIdx.x;  // float4 index, 0..524287
  const int t4 = f & 511;
  const int c = f >> 9;  // n*256 + ch
  const int n = c >> 8, ch = c & 255;
  const int nh = n * 8 + (ch >> 5), d = ch & 31;
  float4 o = {0.f, 0.f, 0.f, 0.f}, l = {0.f, 0.f, 0.f, 0.f};
#pragma unroll
  for (int ks = 0; ks < KS; ++ks) {
    const float4 ov = *(const float4*)(opart + ((size_t)(ks * 32 + nh) * 32 + d) * 2048 + t4 * 4);
    const float4 lv = *(const float4*)(lpart + (size_t)(ks * 32 + nh) * 2048 + t4 * 4);
    o.x += ov.x; o.y += ov.y; o.z += ov.z; o.w += ov.w;
    l.x += lv.x; l.y += lv.y; l.z += lv.z; l.w += lv.w;
  }
  float4 r;
  r.x = o.x / l.x; r.y = o.y / l.y; r.z = o.z / l.z; r.w = o.w / l.w;
  *(float4*)(out + (size_t)f * 4) = r;
}

extern "C" void kernel_launch(void* const* d_in, const int* in_sizes, int n_in,
                              void* d_out, int out_size, void* d_ws, size_t ws_size,
                              hipStream_t stream) {
  const float* x = (const float*)d_in[0];
  const float* Wq = (const float*)d_in[1];
  const float* Wk = (const float*)d_in[2];
  const float* Wv = (const float*)d_in[3];
  unsigned short* ws = (unsigned short*)d_ws;
  float* out = (float*)d_out;
  (void)in_sizes; (void)n_in; (void)out_size;

  pack_kernel<<<1120, 256, 0, stream>>>(x, Wq, Wk, Wv, ws);
  proj_kernel<<<dim3(64, 4, 3), 256, 0, stream>>>(ws);

  char* wsb = (char*)d_ws;
  float* opart = (float*)(wsb + WS_OP);
  if (ws_size >= ((size_t)54u << 20)) {
    float* lpart = (float*)(wsb + WS_OP + ((size_t)4 * 8u << 20));
    attn_kernel<4><<<dim3(16, 32, 4), 256, 0, stream>>>(ws, out, opart, lpart);
    finalize_kernel<4><<<2048, 256, 0, stream>>>(opart, lpart, out);
  } else if (ws_size >= ((size_t)38u << 20)) {
    float* lpart = (float*)(wsb + WS_OP + ((size_t)2 * 8u << 20));
    attn_kernel<2><<<dim3(16, 32, 2), 256, 0, stream>>>(ws, out, opart, lpart);
    finalize_kernel<2><<<2048, 256, 0, stream>>>(opart, lpart, out);
  } else {
    attn_kernel<1><<<dim3(16, 32, 1), 256, 0, stream>>>(ws, out, nullptr, nullptr);
  }
}

// Round 5
// 111.194 us; speedup vs baseline: 1.6340x; 1.6340x over previous
//
#include <hip/hip_runtime.h>

// MultiHeadAttn1D: N=4, C=256, T=2048, H=8, dk=dv=32.
// ws layout (bytes):
//   [0   , 4Mi ) Q_ws  bf16 B-frag (16x16x32): [nh(32)][qtile(128)][lane(64)][8]
//                lane=(t&15)+16*(d>>3), j=d&7   (Q pre-scaled by log2e/sqrt(32))
//   [4Mi , 8Mi ) K_ws  bf16 A-frag (16x16x32): [nh][ktile(128)][lane][8]
//   [8Mi ,12Mi ) V_ws  bf16 B-frag (16x16x16): [nh][kb(32)][dt(2)][sbp(2)][lane][8]
//   [12Mi,16Mi ) Xb    bf16 A-frag x: [n(4)][tt(128)][kc(8)][lane][8]
//   [16Mi,16.4Mi) Wb   bf16 B-frag W: [wi(3)][ot(16)][kc(8)][lane][8]
//   [20Mi, +KS*4Mi)        O_part bf16 [ks][nh][d(32)][t(2048)]    (KS>1 only)
//   [20Mi+KS*4Mi, +KS*256Ki) l_part fp32 [ks][nh][t(2048)]         (KS>1 only)

typedef float f32x4 __attribute__((ext_vector_type(4)));
typedef short short8 __attribute__((ext_vector_type(8)));
typedef short short4v __attribute__((ext_vector_type(4)));

#define WS_Q 0u
#define WS_K (4u << 20)
#define WS_V (8u << 20)
#define WS_X (12u << 20)
#define WS_W (16u << 20)
#define WS_OP (20u << 20)

__device__ __forceinline__ unsigned short f2bf(float f) {
  unsigned int u = __builtin_bit_cast(unsigned int, f);
  u += 0x7FFFu + ((u >> 16) & 1u);
  return (unsigned short)(u >> 16);
}

// pack two floats to bf16 into one dword: [bf(a) | bf(b)<<16]
__device__ __forceinline__ int pack_bf16rn(float a, float b) {
  unsigned int ua = __builtin_bit_cast(unsigned int, a) + 0x8000u;
  unsigned int ub = __builtin_bit_cast(unsigned int, b) + 0x8000u;
  return __builtin_amdgcn_perm(ub, ua, 0x07060302);
}

// ---------------- pack: x -> Xb (bf16 A-frags), W -> Wb (bf16 B-frags) ---------
__global__ __launch_bounds__(256) void pack_kernel(
    const float* __restrict__ x, const float* __restrict__ Wq,
    const float* __restrict__ Wk, const float* __restrict__ Wv,
    unsigned short* __restrict__ ws) {
  const int tid = threadIdx.x;
  const int lane = tid & 63;
  const int wv = tid >> 6;
  const int lc = lane & 15, lq = lane >> 4;
  const int b = blockIdx.x;
  alignas(16) unsigned short tmp[8];
  if (b < 1024) {
    const int r = b * 4 + wv;  // 0..4095 = (n,tt,kc)
    const int kc = r & 7, tt = (r >> 3) & 127, n = r >> 10;
    const int t = tt * 16 + lc;
    const int c0 = kc * 32 + lq * 8;
    const float* src = x + (size_t)(n * 256 + c0) * 2048 + t;
#pragma unroll
    for (int j = 0; j < 8; ++j) tmp[j] = f2bf(src[(size_t)j * 2048]);
    unsigned short* dst = ws + (WS_X >> 1) + (size_t)r * 512 + lane * 8;
    *(int4*)dst = *(const int4*)tmp;
  } else {
    const int r = (b - 1024) * 4 + wv;  // 0..383 = (wi,ot,kc)
    const int kc = r & 7, ot = (r >> 3) & 15, wi = r >> 7;
    const float* W = (wi == 0) ? Wq : (wi == 1) ? Wk : Wv;
    const float scale = (wi == 0) ? 0.25503492f : 1.0f;  // log2(e)/sqrt(32)
    const int o = ot * 16 + lc;
    const int c0 = kc * 32 + lq * 8;
    const float* src = W + o * 256 + c0;
#pragma unroll
    for (int j = 0; j < 8; ++j) tmp[j] = f2bf(src[j] * scale);
    unsigned short* dst = ws + (WS_W >> 1) + (size_t)r * 512 + lane * 8;
    *(int4*)dst = *(const int4*)tmp;
  }
}

// ---------------- projection GEMM: Q/K/V = W * x, frag-packed outputs ----------
__global__ __launch_bounds__(256) void proj_kernel(unsigned short* __restrict__ ws) {
  __shared__ unsigned short eps[4][2048];  // per-wave 4KB swizzle buffer (Q/K only)
  const int tid = threadIdx.x, lane = tid & 63, w = tid >> 6;
  const int lc = lane & 15, lq = lane >> 4;
  const int tt2 = blockIdx.x;  // 0..63 : t-range of 32
  const int n = blockIdx.y;    // 0..3
  const int wi = blockIdx.z;   // 0=Q 1=K 2=V
  const unsigned short* Xb = ws + (WS_X >> 1);
  const unsigned short* Wb = ws + (WS_W >> 1);

  short8 af[2][8];
#pragma unroll
  for (int mt = 0; mt < 2; ++mt)
#pragma unroll
    for (int kc = 0; kc < 8; ++kc)
      af[mt][kc] = *(const short8*)(Xb + ((size_t)((n * 128 + tt2 * 2 + mt) * 8 + kc) * 512 + lane * 8));

  f32x4 acc[2][4];
#pragma unroll
  for (int mt = 0; mt < 2; ++mt)
#pragma unroll
    for (int nt = 0; nt < 4; ++nt) {
      f32x4 z = {0.f, 0.f, 0.f, 0.f};
      acc[mt][nt] = z;
    }

#pragma unroll
  for (int kc = 0; kc < 8; ++kc) {
    short8 bf[4];
#pragma unroll
    for (int nt = 0; nt < 4; ++nt)
      bf[nt] = *(const short8*)(Wb + ((size_t)((wi * 16 + w * 4 + nt) * 8 + kc) * 512 + lane * 8));
#pragma unroll
    for (int mt = 0; mt < 2; ++mt)
#pragma unroll
      for (int nt = 0; nt < 4; ++nt)
        acc[mt][nt] = __builtin_amdgcn_mfma_f32_16x16x32_bf16(af[mt][kc], bf[nt], acc[mt][nt], 0, 0, 0);
  }

  // C layout: value (mt,nt,r) at lane(lc,lq) is element (t = tt2*32+mt*16+lq*4+r,
  //                                                      o = w*64+nt*16+lc)
  if (wi < 2) {
    unsigned short* ep = eps[w];
#pragma unroll
    for (int mt = 0; mt < 2; ++mt)
#pragma unroll
      for (int nt = 0; nt < 4; ++nt) {
        const int m2 = ((nt & 1) << 1) | (lc >> 3);
        const int base = ((mt * 2 + (nt >> 1)) << 9) + (m2 << 7) + (lq << 5) + (lc & 7);
#pragma unroll
        for (int r = 0; r < 4; ++r)
          ep[base + ((r ^ m2) << 3)] = f2bf(acc[mt][nt][r]);
      }
    const int swzl = lane ^ (lane >> 4);
    unsigned short* dst = ws + ((wi == 0) ? (WS_Q >> 1) : (WS_K >> 1));
#pragma unroll
    for (int rl = 0; rl < 4; ++rl) {
      int4 v = *(const int4*)(ep + (rl << 9) + swzl * 8);
      const int mt = rl >> 1, hh = rl & 1;
      const int nh = n * 8 + w * 2 + hh;
      const int ttg = tt2 * 2 + mt;
      *(int4*)(dst + ((size_t)(nh * 128 + ttg) * 64 + lane) * 8) = v;
    }
  } else {
    // V: target [nh][kb][dt][sbp][lane][half*4+j] -- lane mapping is IDENTITY.
    const int kb = tt2 >> 1, sbp = tt2 & 1;
#pragma unroll
    for (int nt = 0; nt < 4; ++nt) {
      const int nh = n * 8 + w * 2 + (nt >> 1);
      const int dt = nt & 1;
      alignas(16) unsigned short tmp[8];
#pragma unroll
      for (int mt = 0; mt < 2; ++mt)
#pragma unroll
        for (int r = 0; r < 4; ++r) tmp[mt * 4 + r] = f2bf(acc[mt][nt][r]);
      unsigned short* dstv = ws + (WS_V >> 1) +
          ((size_t)((((nh * 32 + kb) * 2 + dt) * 2 + sbp)) * 64 + lane) * 8;
      *(int4*)dstv = *(const int4*)tmp;
    }
  }
}

// ------ fused flash attention: split-K, barrier-free, XCD-pinned chunks -------
// 1D grid, blockIdx.x = qx*CH + c, chunk id c = ks*32+nh. linear%8 = nh&7 ->
// all blocks touching head nh land on one XCD: K/V/Q chunk fetched into that
// XCD's L2 once (~1.5MB/XCD) instead of 8x duplication (R4: FETCH 121MB).
// Waves are fully independent (no LDS, no barriers) -> TLP hides L2 latency.
template <int KS>
__global__ __launch_bounds__(128, 5) void attn_kernel(
    const unsigned short* __restrict__ ws, float* __restrict__ out,
    unsigned short* __restrict__ opart, float* __restrict__ lpart) {
  const int tid = threadIdx.x;
  const int lane = tid & 63, wv = tid >> 6;
  const int lc = lane & 15, quad = lane >> 4;
  constexpr int CH = 32 * KS;
  const int c = blockIdx.x & (CH - 1);
  const int qx = blockIdx.x / CH;   // 0..31
  const int nh = c & 31;            // chunk -> XCD pin: nh&7
  const int ks = c >> 5;            // 0..KS-1
  const int qw = qx * 2 + wv;       // 0..63 -> q rows qw*32 .. +31
  constexpr int NKB = 32 / KS;
  const int kb0 = ks * NKB;

  const unsigned short* Qw = ws + (WS_Q >> 1) + ((size_t)(nh * 128 + qw * 2)) * 512;
  const unsigned short* Kb = ws + (WS_K >> 1) + (size_t)nh * 65536;
  const unsigned short* Vb = ws + (WS_V >> 1) + (size_t)nh * 65536;

  // Q B-frags (16x16x32): n=query on lane&15, k=dk on quad*8+j. Loaded once.
  short8 qf[2];
  qf[0] = *(const short8*)(Qw + lane * 8);
  qf[1] = *(const short8*)(Qw + 512 + lane * 8);

  f32x4 acc[2][2];
#pragma unroll
  for (int mt = 0; mt < 2; ++mt)
#pragma unroll
    for (int dt = 0; dt < 2; ++dt) {
      f32x4 z = {0.f, 0.f, 0.f, 0.f};
      acc[mt][dt] = z;
    }
  float lsum[2] = {0.f, 0.f};

  for (int kb = kb0; kb < kb0 + NKB; ++kb) {
    const unsigned short* kp = Kb + (size_t)kb * 2048 + lane * 8;
    const unsigned short* vp = Vb + (size_t)kb * 2048 + lane * 8;
    // coalesced 16B/lane loads, L2-resident after XCD pinning
    short8 kf[4], vvr[4];
#pragma unroll
    for (int sb = 0; sb < 4; ++sb) kf[sb] = *(const short8*)(kp + sb * 512);
#pragma unroll
    for (int u = 0; u < 4; ++u) vvr[u] = *(const short8*)(vp + u * 512);

    // S^T = K * Q^T via 16x16x32: A=K-frag (m=key), B=Q-frag (n=query)
    // C-layout of S^T (col=query, row=key quad*4+r) == A-frag layout of 16x16x16.
    short4v pf[2][4];
#pragma unroll
    for (int mt = 0; mt < 2; ++mt) {
      f32x4 st[4];
#pragma unroll
      for (int sb = 0; sb < 4; ++sb) {
        f32x4 z = {0.f, 0.f, 0.f, 0.f};
        st[sb] = __builtin_amdgcn_mfma_f32_16x16x32_bf16(kf[sb], qf[mt], z, 0, 0, 0);
      }
#pragma unroll
      for (int sb = 0; sb < 4; ++sb) {
        float p0 = __builtin_amdgcn_exp2f(st[sb][0]);
        float p1 = __builtin_amdgcn_exp2f(st[sb][1]);
        float p2 = __builtin_amdgcn_exp2f(st[sb][2]);
        float p3 = __builtin_amdgcn_exp2f(st[sb][3]);
        lsum[mt] += (p0 + p1) + (p2 + p3);
        int2 pi;
        pi.x = pack_bf16rn(p0, p1);
        pi.y = pack_bf16rn(p2, p3);
        pf[mt][sb] = __builtin_bit_cast(short4v, pi);
      }
    }

    // O += P * V via 16x16x16 (V B-frag prepacked: n=d on lane&15, k=key)
    short4v vf[4][2];
#pragma unroll
    for (int dt = 0; dt < 2; ++dt)
#pragma unroll
      for (int sbp = 0; sbp < 2; ++sbp) {
        short8 t = vvr[dt * 2 + sbp];
        vf[sbp * 2 + 0][dt] = __builtin_shufflevector(t, t, 0, 1, 2, 3);
        vf[sbp * 2 + 1][dt] = __builtin_shufflevector(t, t, 4, 5, 6, 7);
      }
#pragma unroll
    for (int sb = 0; sb < 4; ++sb)
#pragma unroll
      for (int mt = 0; mt < 2; ++mt) {
        acc[mt][0] = __builtin_amdgcn_mfma_f32_16x16x16bf16_1k(pf[mt][sb], vf[sb][0], acc[mt][0], 0, 0, 0);
        acc[mt][1] = __builtin_amdgcn_mfma_f32_16x16x16bf16_1k(pf[mt][sb], vf[sb][1], acc[mt][1], 0, 0, 0);
      }
  }

  // finish row sums across quads
#pragma unroll
  for (int mt = 0; mt < 2; ++mt) {
    lsum[mt] += __shfl_xor(lsum[mt], 16);
    lsum[mt] += __shfl_xor(lsum[mt], 32);
  }

  if constexpr (KS == 1) {
    // normalize + direct store. acc C-layout: col=lc=d, row=quad*4+r=q (+mt*16)
    const int chbase = (nh >> 3) * 256 + (nh & 7) * 32;
#pragma unroll
    for (int mt = 0; mt < 2; ++mt) {
      float is[4];
#pragma unroll
      for (int r = 0; r < 4; ++r) is[r] = 1.0f / __shfl(lsum[mt], quad * 4 + r);
      const int tb = qw * 32 + mt * 16 + quad * 4;
#pragma unroll
      for (int dt = 0; dt < 2; ++dt) {
        f32x4 ov;
#pragma unroll
        for (int r = 0; r < 4; ++r) ov[r] = acc[mt][dt][r] * is[r];
        *(f32x4*)(out + (size_t)(chbase + dt * 16 + lc) * 2048 + tb) = ov;
      }
    }
  } else {
    // store UNnormalized bf16 partials (halved traffic); finalize combines.
    const size_t ob = (size_t)(ks * 32 + nh) * 32 * 2048;  // shorts
#pragma unroll
    for (int mt = 0; mt < 2; ++mt) {
      const int tb = qw * 32 + mt * 16 + quad * 4;
#pragma unroll
      for (int dt = 0; dt < 2; ++dt) {
        int2 pi;
        pi.x = pack_bf16rn(acc[mt][dt][0], acc[mt][dt][1]);
        pi.y = pack_bf16rn(acc[mt][dt][2], acc[mt][dt][3]);
        *(int2*)(opart + ob + (size_t)(dt * 16 + lc) * 2048 + tb) = pi;
      }
      if (quad == 0)
        lpart[(size_t)(ks * 32 + nh) * 2048 + qw * 32 + mt * 16 + lc] = lsum[mt];
    }
  }
}

// ---------------- finalize: out = (sum_ks O_part) / (sum_ks l_part) -----------
template <int KS>
__global__ __launch_bounds__(256) void finalize_kernel(
    const unsigned short* __restrict__ opart, const float* __restrict__ lpart,
    float* __restrict__ out) {
  const int f = blockIdx.x * 256 + threadIdx.x;  // float4 index, 0..524287
  const int t4 = f & 511;
  const int c = f >> 9;  // n*256 + ch
  const int n = c >> 8, ch = c & 255;
  const int nh = n * 8 + (ch >> 5), d = ch & 31;
  float o[4] = {0.f, 0.f, 0.f, 0.f};
  float l[4] = {0.f, 0.f, 0.f, 0.f};
#pragma unroll
  for (int ks = 0; ks < KS; ++ks) {
    const short4v ov = *(const short4v*)(opart + ((size_t)(ks * 32 + nh) * 32 + d) * 2048 + t4 * 4);
    const float4 lv = *(const float4*)(lpart + (size_t)(ks * 32 + nh) * 2048 + t4 * 4);
#pragma unroll
    for (int i = 0; i < 4; ++i) {
      const unsigned int u = ((unsigned int)(unsigned short)ov[i]) << 16;
      o[i] += __builtin_bit_cast(float, u);
    }
    l[0] += lv.x; l[1] += lv.y; l[2] += lv.z; l[3] += lv.w;
  }
  float4 r;
  r.x = o[0] / l[0]; r.y = o[1] / l[1]; r.z = o[2] / l[2]; r.w = o[3] / l[3];
  *(float4*)(out + (size_t)f * 4) = r;
}

extern "C" void kernel_launch(void* const* d_in, const int* in_sizes, int n_in,
                              void* d_out, int out_size, void* d_ws, size_t ws_size,
                              hipStream_t stream) {
  const float* x = (const float*)d_in[0];
  const float* Wq = (const float*)d_in[1];
  const float* Wk = (const float*)d_in[2];
  const float* Wv = (const float*)d_in[3];
  unsigned short* ws = (unsigned short*)d_ws;
  float* out = (float*)d_out;
  (void)in_sizes; (void)n_in; (void)out_size;

  pack_kernel<<<1120, 256, 0, stream>>>(x, Wq, Wk, Wv, ws);
  proj_kernel<<<dim3(64, 4, 3), 256, 0, stream>>>(ws);

  char* wsb = (char*)d_ws;
  unsigned short* opart = (unsigned short*)(wsb + WS_OP);
  if (ws_size >= ((size_t)41u << 20)) {
    float* lpart = (float*)(wsb + WS_OP + ((size_t)4 * 4u << 20));
    attn_kernel<4><<<4096, 128, 0, stream>>>(ws, out, opart, lpart);
    finalize_kernel<4><<<2048, 256, 0, stream>>>(opart, lpart, out);
  } else if (ws_size >= ((size_t)30u << 20)) {
    float* lpart = (float*)(wsb + WS_OP + ((size_t)2 * 4u << 20));
    attn_kernel<2><<<2048, 128, 0, stream>>>(ws, out, opart, lpart);
    finalize_kernel<2><<<2048, 256, 0, stream>>>(opart, lpart, out);
  } else {
    attn_kernel<1><<<1024, 128, 0, stream>>>(ws, out, nullptr, nullptr);
  }
}